// Round 8
// baseline (7630.173 us; speedup 1.0000x reference)
//
#include <hip/hip_runtime.h>
#include <math.h>

// Problem dims
#define B_SZ   32
#define T_SZ   512
#define I_DIM  256
#define H_DIM  1024
#define P_DIM  512
#define G4     4096   // 4*H
#define O_DIM  256

// Workspace layout (bytes)
#define WS_RRBP      0            // 8 MB  RR packed B-fragments (bf16)
#define WS_WP_HI     8388608      // 1 MB
#define WS_WP_LO     9437184      // 1 MB
#define WS_RT_HI     10485760     // 4 MB  R^T planes [4096][512]
#define WS_RT_LO     14680064     // 4 MB
#define WS_WT_HI     18874368     // 2 MB  W^T planes [4096][256]
#define WS_WT_LO     20971520     // 2 MB
#define WS_IN_HI     23068672     // 8 MB  inputs planes row-major
#define WS_IN_LO     31457280     // 8 MB
#define WS_WPT       39845888     // 1 MB  W_proj^T bf16 [512][1024]
#define WS_LWB       40894464     // 256 KB lin_w bf16 [256][512]
#define WS_DONEG     41943040     // 4 x 8 KB group step flags
#define WS_PREADY    41975808     // 8 KB  producer chunk-ready
#define WS_CDONE     41984000     // 8 KB  consumer chunk-done
#define WS_HPK0      42991616     // 128 KB h frag-packed ping [4 grp][32 kt][64][8]
#define WS_HPK1      43122688     // 128 KB h frag-packed pong
#define WS_HBF       44040192     // 32 MB h_seq bf16 [512][32][1024]
#define WS_XG0       77594624     // 32 MB xg chunk buffer 0 (f32)
#define WS_XG1       111149056    // 32 MB xg chunk buffer 1 (f32)
#define WS_HPBF      144703488    // 16 MB hp bf16 [16384][512]
#define WS_RRBUF     144703488    // 16 MB RR f32 (pre-persistent only; overlaps HPBF)

typedef short short8 __attribute__((ext_vector_type(8)));
typedef float f32x4  __attribute__((ext_vector_type(4)));
typedef unsigned long long u64;

__device__ __forceinline__ float sigmf(float x) { return 1.0f / (1.0f + __expf(-x)); }
__device__ __forceinline__ float tanhfast(float x) { return 1.0f - 2.0f / (__expf(2.0f * x) + 1.0f); }
__device__ __forceinline__ short f2bf(float f) {
    union { float f; unsigned u; } v; v.f = f;
    unsigned r = (v.u + 0x7FFF + ((v.u >> 16) & 1)) >> 16;
    return (short)r;
}
__device__ __forceinline__ float bf2f(short h) {
    union { unsigned u; float f; } v; v.u = ((unsigned)(unsigned short)h) << 16;
    return v.f;
}

// 16B load that bypasses caches (agent-scope relaxed atomics -> coherence point)
__device__ __forceinline__ short8 ld_bypass16(const u64* p)
{
    union { u64 q[2]; short8 v; } u;
    u.q[0] = __hip_atomic_load(p,     __ATOMIC_RELAXED, __HIP_MEMORY_SCOPE_AGENT);
    u.q[1] = __hip_atomic_load(p + 1, __ATOMIC_RELAXED, __HIP_MEMORY_SCOPE_AGENT);
    return u.v;
}

// ---------------------------------------------------------------------------
__global__ void split_copy(const float* __restrict__ in, short* __restrict__ hi,
                           short* __restrict__ lo, int n)
{
    int i = blockIdx.x * 256 + threadIdx.x;
    if (i < n) {
        float v = in[i];
        short h = f2bf(v);
        hi[i] = h;
        if (lo) lo[i] = f2bf(v - bf2f(h));
    }
}

__global__ void transpose_split(const float* __restrict__ in, short* __restrict__ hi,
                                short* __restrict__ lo, int rows, int cols)
{
    __shared__ float t[32][33];
    int c0 = blockIdx.x * 32, r0 = blockIdx.y * 32;
    int x = threadIdx.x, y = threadIdx.y;   // 32 x 8
    #pragma unroll
    for (int i = y; i < 32; i += 8) t[i][x] = in[(size_t)(r0 + i) * cols + c0 + x];
    __syncthreads();
    #pragma unroll
    for (int i = y; i < 32; i += 8) {
        float v = t[x][i];
        short h = f2bf(v);
        size_t o = (size_t)(c0 + i) * rows + r0 + x;
        hi[o] = h;
        if (lo) lo[o] = f2bf(v - bf2f(h));
    }
}

// ---------------------------------------------------------------------------
// MFMA bf16 GEMM tile body (one 128x128 C tile at m0,n0). Same as rounds 4-7.
// ---------------------------------------------------------------------------
template<int SPLIT, int AMODE, int CMODE, int BIAS>
__device__ __forceinline__
void gemm_tile(const short* __restrict__ Ah, const short* __restrict__ Al,
               const short* __restrict__ Bh, const short* __restrict__ Bl,
               const float* __restrict__ bias, void* __restrict__ Cp,
               int N, int K, int t0, int m0, int n0)
{
    __shared__ short As[SPLIT + 1][8192];   // [plane][row*64 + k], 16KB each
    __shared__ short Bs[SPLIT + 1][8192];
    const int tid = threadIdx.x;
    const int l   = tid & 63;
    const int w   = tid >> 6;
    const int wm  = w & 1, wn = w >> 1;

    f32x4 acc[4][4] = {};

    for (int k0 = 0; k0 < K; k0 += 64) {
        __syncthreads();
        #pragma unroll
        for (int q = 0; q < 4; q++) {
            int rg   = q * 4 + w;
            int rr   = (rg << 3) + (l >> 3);
            int slot = (l & 7) ^ (rr & 7);        // pre-swizzled source slot
            int lidx = rg * 512 + l * 8;          // linear LDS dest (shorts)
            size_t aoff, boff;
            int ra = m0 + rr, rb = n0 + rr;
            if constexpr (AMODE == 1)
                aoff = (size_t)((ra & 31) * 512 + t0 + (ra >> 5)) * 256 + k0 + slot * 8;
            else
                aoff = (size_t)ra * K + k0 + slot * 8;
            boff = (size_t)rb * K + k0 + slot * 8;
            __builtin_amdgcn_global_load_lds(Ah + aoff, &As[0][lidx], 16, 0, 0);
            __builtin_amdgcn_global_load_lds(Bh + boff, &Bs[0][lidx], 16, 0, 0);
            if constexpr (SPLIT) {
                __builtin_amdgcn_global_load_lds(Al + aoff, &As[1][lidx], 16, 0, 0);
                __builtin_amdgcn_global_load_lds(Bl + boff, &Bs[1][lidx], 16, 0, 0);
            }
        }
        __syncthreads();

        #pragma unroll
        for (int ks = 0; ks < 2; ks++) {
            const int cb = (((ks * 4) + (l >> 4)) ^ (l & 7)) * 16;  // swizzled col byte
            short8 af[4], bfr[4], afl[4], bfl[4];
            #pragma unroll
            for (int mf = 0; mf < 4; mf++) {
                int mloc = wm * 64 + mf * 16 + (l & 15);
                af[mf] = *(const short8*)((const char*)As[0] + mloc * 128 + cb);
                if constexpr (SPLIT)
                    afl[mf] = *(const short8*)((const char*)As[1] + mloc * 128 + cb);
            }
            #pragma unroll
            for (int nf = 0; nf < 4; nf++) {
                int nloc = wn * 64 + nf * 16 + (l & 15);
                bfr[nf] = *(const short8*)((const char*)Bs[0] + nloc * 128 + cb);
                if constexpr (SPLIT)
                    bfl[nf] = *(const short8*)((const char*)Bs[1] + nloc * 128 + cb);
            }
            #pragma unroll
            for (int mf = 0; mf < 4; mf++)
                #pragma unroll
                for (int nf = 0; nf < 4; nf++)
                    acc[mf][nf] = __builtin_amdgcn_mfma_f32_16x16x32_bf16(
                        af[mf], bfr[nf], acc[mf][nf], 0, 0, 0);
            if constexpr (SPLIT) {
                #pragma unroll
                for (int mf = 0; mf < 4; mf++)
                    #pragma unroll
                    for (int nf = 0; nf < 4; nf++)
                        acc[mf][nf] = __builtin_amdgcn_mfma_f32_16x16x32_bf16(
                            af[mf], bfl[nf], acc[mf][nf], 0, 0, 0);
                #pragma unroll
                for (int mf = 0; mf < 4; mf++)
                    #pragma unroll
                    for (int nf = 0; nf < 4; nf++)
                        acc[mf][nf] = __builtin_amdgcn_mfma_f32_16x16x32_bf16(
                            afl[mf], bfr[nf], acc[mf][nf], 0, 0, 0);
            }
        }
    }

    float bv[4];
    if constexpr (BIAS) {
        #pragma unroll
        for (int nf = 0; nf < 4; nf++)
            bv[nf] = bias[n0 + wn * 64 + nf * 16 + (l & 15)];
    }
    #pragma unroll
    for (int mf = 0; mf < 4; mf++) {
        #pragma unroll
        for (int r = 0; r < 4; r++) {
            int row = m0 + wm * 64 + mf * 16 + (l >> 4) * 4 + r;
            #pragma unroll
            for (int nf = 0; nf < 4; nf++) {
                int col = n0 + wn * 64 + nf * 16 + (l & 15);
                float v = acc[mf][nf][r];
                if constexpr (BIAS) v += bv[nf];
                if constexpr (CMODE == 0)
                    ((float*)Cp)[(size_t)row * N + col] = v;
                else if constexpr (CMODE == 1)
                    ((short*)Cp)[(size_t)row * N + col] = f2bf(v);
                else
                    ((float*)Cp)[(size_t)(row & 31) * (T_SZ * O_DIM)
                                 + (size_t)(row >> 5) * O_DIM + col] = v;
            }
        }
    }
}

// ---- concrete (non-template) kernel entry points ----
__global__ __launch_bounds__(256)
void gemm_rr(const short* Ah, const short* Al, const short* Bh, const short* Bl,
             const float* bias, void* Cp, int N, int K, int t0)
{ gemm_tile<1, 0, 0, 0>(Ah, Al, Bh, Bl, bias, Cp, N, K, t0, blockIdx.y * 128, blockIdx.x * 128); }

__global__ __launch_bounds__(256)
void gemm_proj(const short* Ah, const short* Al, const short* Bh, const short* Bl,
               const float* bias, void* Cp, int N, int K, int t0)
{ gemm_tile<0, 0, 1, 0>(Ah, Al, Bh, Bl, bias, Cp, N, K, t0, blockIdx.y * 128, blockIdx.x * 128); }

__global__ __launch_bounds__(256)
void gemm_out(const short* Ah, const short* Al, const short* Bh, const short* Bl,
              const float* bias, void* Cp, int N, int K, int t0)
{ gemm_tile<0, 0, 2, 1>(Ah, Al, Bh, Bl, bias, Cp, N, K, t0, blockIdx.y * 128, blockIdx.x * 128); }

// ---------------------------------------------------------------------------
__global__ __launch_bounds__(256)
void pack_rr(const float* __restrict__ RRf, short* __restrict__ RRbp)
{
    int idx = blockIdx.x * 256 + threadIdx.x;     // short8 slot, 0..524287
    int lane = idx & 63;
    int kt   = (idx >> 6) & 31;
    int wn   = (idx >> 11) & 1;
    int blk  = idx >> 12;
    int nl = wn * 16 + (lane & 15);
    int g = nl >> 3, jl = nl & 7;
    int col = g * 1024 + blk * 8 + jl;
    int kbase = kt * 32 + (lane >> 4) * 8;
    short8 v;
    #pragma unroll
    for (int i = 0; i < 8; i++)
        v[i] = f2bf(RRf[(size_t)(kbase + i) * G4 + col]);
    ((short8*)RRbp)[idx] = v;
}

// ---------------------------------------------------------------------------
__device__ __forceinline__ void waitall(int* slots, int tid, int target, bool fence)
{
    if (tid < 64) {
        const int i0 = (tid * 2) * 16, i1 = (tid * 2 + 1) * 16;
        for (;;) {
            int v0 = __hip_atomic_load(&slots[i0], __ATOMIC_RELAXED, __HIP_MEMORY_SCOPE_AGENT);
            int v1 = __hip_atomic_load(&slots[i1], __ATOMIC_RELAXED, __HIP_MEMORY_SCOPE_AGENT);
            if (__all(v0 >= target && v1 >= target)) break;
            __builtin_amdgcn_s_sleep(1);
        }
        if (fence) __threadfence();   // heavy acquire: only at chunk handoff
    }
    __syncthreads();
}

// Post own flag to postArr, then wait all 128 slots of waitArr >= wtarget.
// RELAXED flags: the leading __syncthreads drains bypass stores first.
__device__ __forceinline__ void post_wait(int* postArr, int* waitArr, int bid,
                                          int tid, int ptarget, int wtarget)
{
    __syncthreads();
    if (tid == 0)
        __hip_atomic_store(&postArr[bid * 16], ptarget,
                           __ATOMIC_RELAXED, __HIP_MEMORY_SCOPE_AGENT);
    if (tid < 64) {
        const int i0 = (tid * 2) * 16, i1 = (tid * 2 + 1) * 16;
        for (;;) {
            int v0 = __hip_atomic_load(&waitArr[i0], __ATOMIC_RELAXED, __HIP_MEMORY_SCOPE_AGENT);
            int v1 = __hip_atomic_load(&waitArr[i1], __ATOMIC_RELAXED, __HIP_MEMORY_SCOPE_AGENT);
            if (__all(v0 >= wtarget && v1 >= wtarget)) break;
            __builtin_amdgcn_s_sleep(1);
        }
    }
    __syncthreads();
}

// ---------------------------------------------------------------------------
// Persistent kernel, 256 blocks x 256 threads (1 block/CU).
// Blocks 128..255: producers — xg chunks into xg0/xg1 (double buffer).
// Blocks 0..127: consumers — FOUR independent 8-batch recurrence chains
// (G=4) in rotating phases; 3 phases of slack hide the ~3.7us flag
// propagation. RR B-fragments live in VGPRs for the whole sequence.
// Batch rows padded 8->16 in the MFMA fragment by duplicate stores.
// ---------------------------------------------------------------------------
__global__ __launch_bounds__(256, 1)
void lstm_persistent(const short* __restrict__ in_hi, const short* __restrict__ in_lo,
                     const short* __restrict__ Wt_hi, const short* __restrict__ Wt_lo,
                     const float* __restrict__ bvec,
                     const short* __restrict__ RRbp,
                     float* __restrict__ xg0, float* __restrict__ xg1,
                     short* __restrict__ hpk0, short* __restrict__ hpk1,
                     short* __restrict__ h_bf,
                     const float* __restrict__ p,
                     int* __restrict__ doneG,      // 4 arrays, stride 2048 ints
                     int* __restrict__ pready, int* __restrict__ cdone)
{
    const int tid = threadIdx.x;
    const int bid = blockIdx.x;

    if (bid >= 128) {
        // ---------------- producers ----------------
        const int pb = bid - 128;
        for (int chunk = 0; chunk < 8; chunk++) {
            if (chunk >= 2) waitall(cdone, tid, chunk - 1, false);  // buf free?
            float* xgc = (chunk & 1) ? xg1 : xg0;
            #pragma unroll 1
            for (int q = 0; q < 4; q++) {
                int ti = pb * 4 + q;                   // 0..511 tiles (16m x 32n)
                gemm_tile<1, 1, 0, 1>(in_hi, in_lo, Wt_hi, Wt_lo, bvec, xgc,
                                      G4, I_DIM, chunk * 64,
                                      (ti >> 5) * 128, (ti & 31) * 128);
            }
            __syncthreads();
            if (tid == 0)   // agent release: L2 writeback so xg is visible
                __hip_atomic_store(&pready[pb * 16], chunk + 1,
                                   __ATOMIC_RELEASE, __HIP_MEMORY_SCOPE_AGENT);
        }
        return;
    }

    // ---------------- consumers: recurrence ----------------
    __shared__ float zbuf[2][16][33];     // [k-half partial][frag row][gatecol]
    const int lane = tid & 63;
    const int w    = tid >> 6;
    const int wnp  = w & 1;               // col half (gates i,f | g,o)
    const int kq   = w >> 1;              // k half
    const int eb   = tid >> 3;            // local batch 0..7 (valid when tid<64)
    const int ejl  = tid & 7;
    const int ej   = bid * 8 + ejl;       // h-dim index owned by this thread
    const bool act = (tid < 64);
    float cvs[4] = {0.f, 0.f, 0.f, 0.f};  // cell state per batch group
    const float pi = p[ej], pf = p[1024 + ej], po = p[2048 + ej];
    const int lane2 = (eb & 7) | (((ej & 31) >> 3) << 4);   // frag row (low copy)
    const int kt2   = ej >> 5;

    // RR B-fragments resident in VGPRs: this wave's (wnp, kq) slice, 16 frags
    short8 brs[16];
    {
        const short8* BpBase = (const short8*)RRbp
            + ((size_t)(bid * 2 + wnp) * 32 + kq * 16) * 64 + lane;
        #pragma unroll
        for (int i = 0; i < 16; i++) brs[i] = BpBase[(size_t)i * 64];
    }

    auto phase = [&](int g, int t, const short* hin, short* hout,
                     const float* xg_t, float& cv) {
        // xg prefetch (latency hides under A-loads + MFMA)
        float xzi = 0.f, xzf = 0.f, xzg = 0.f, xzo = 0.f;
        if (act) {
            const float* xr = xg_t + (size_t)(g * 8 + eb) * G4 + ej;
            xzi = xr[0]; xzf = xr[1024]; xzg = xr[2048]; xzo = xr[3072];
        }
        const u64* Ap = (const u64*)hin + (size_t)(((g * 32 + kq * 16) * 64) + lane) * 2;
        f32x4 a0 = {0.f, 0.f, 0.f, 0.f};
        f32x4 a1 = {0.f, 0.f, 0.f, 0.f};
        #pragma unroll
        for (int i = 0; i < 8; i++) {
            short8 av = ld_bypass16(Ap + (size_t)i * 128);
            a0 = __builtin_amdgcn_mfma_f32_16x16x32_bf16(av, brs[i], a0, 0, 0, 0);
        }
        #pragma unroll
        for (int i = 8; i < 16; i++) {
            short8 av = ld_bypass16(Ap + (size_t)i * 128);
            a1 = __builtin_amdgcn_mfma_f32_16x16x32_bf16(av, brs[i], a1, 0, 0, 0);
        }
        a0[0] += a1[0]; a0[1] += a1[1]; a0[2] += a1[2]; a0[3] += a1[3];
        {   // C/D: col=lane&15, row=(lane>>4)*4+r (row = frag batch row)
            int col = lane & 15;
            int row = (lane >> 4) * 4;
            #pragma unroll
            for (int r = 0; r < 4; r++)
                zbuf[kq][row + r][wnp * 16 + col] = a0[r];
        }
        __syncthreads();
        if (act) {
            float zi = zbuf[0][eb][ejl]      + zbuf[1][eb][ejl]      + xzi;
            float zf = zbuf[0][eb][8 + ejl]  + zbuf[1][eb][8 + ejl]  + xzf;
            float zg = zbuf[0][eb][16 + ejl] + zbuf[1][eb][16 + ejl] + xzg;
            float zo = zbuf[0][eb][24 + ejl] + zbuf[1][eb][24 + ejl] + xzo;
            float ig = sigmf(zi + cv * pi);
            float fg = sigmf(zf + cv * pf);
            float gg = tanhfast(zg);
            float cn = fg * cv + ig * gg;
            float og = sigmf(zo + cn * po);
            float hv = og * tanhfast(cn);
            cv = cn;
            unsigned hb = (unsigned)(unsigned short)f2bf(hv);
            unsigned other = __shfl_xor(hb, 1);
            if ((tid & 1) == 0) {
                unsigned pk = hb | (other << 16);
                size_t sidx = ((size_t)((g * 32 + kt2) * 64 + lane2)) * 8 + ejl;
                // low copy + duplicate row (+8 lanes = +32 u32) for M=16 padding
                __hip_atomic_store((unsigned*)hout + (sidx >> 1), pk,
                                   __ATOMIC_RELAXED, __HIP_MEMORY_SCOPE_AGENT);
                __hip_atomic_store((unsigned*)hout + (sidx >> 1) + 32, pk,
                                   __ATOMIC_RELAXED, __HIP_MEMORY_SCOPE_AGENT);
                size_t hidx = (size_t)t * (B_SZ * H_DIM) + (size_t)(g * 8 + eb) * H_DIM + ej;
                *((unsigned*)h_bf + (hidx >> 1)) = pk;   // normal store (post-kernel use)
            }
        }
    };

    for (int chunk = 0; chunk < 8; chunk++) {
        waitall(pready, tid, chunk + 1, true);   // heavy acquire (once/chunk)
        const float* xgc = (chunk & 1) ? xg1 : xg0;

        for (int tl = 0; tl < 64; tl++) {
            const int t = chunk * 64 + tl;
            const short* hin = (t & 1) ? hpk1 : hpk0;
            short*      hout = (t & 1) ? hpk0 : hpk1;
            const float* xg_t = xgc + (size_t)tl * (B_SZ * G4);

            // precondition before phase g at step t: doneG[g] >= t (from the
            // boundary 3 phases earlier). G=4 rotation hides flag propagation.
            #pragma unroll
            for (int g = 0; g < 4; g++) {
                phase(g, t, hin, hout, xg_t, cvs[g]);
                int* pa = doneG + g * 2048;
                int* wa = doneG + ((g + 1) & 3) * 2048;
                int wt = (g == 3) ? (t + 1) : t;
                post_wait(pa, wa, bid, tid, t + 1, wt);
            }
        }
        if (tid == 0)
            __hip_atomic_store(&cdone[bid * 16], chunk + 1,
                               __ATOMIC_RELAXED, __HIP_MEMORY_SCOPE_AGENT);
    }
}

// ---------------------------------------------------------------------------
extern "C" void kernel_launch(void* const* d_in, const int* in_sizes, int n_in,
                              void* d_out, int out_size, void* d_ws, size_t ws_size,
                              hipStream_t stream)
{
    const float* inp    = (const float*)d_in[0];  // (32,512,256)
    const float* W      = (const float*)d_in[1];  // (256,4096)
    const float* R      = (const float*)d_in[2];  // (512,4096)
    const float* W_proj = (const float*)d_in[3];  // (1024,512)
    const float* p      = (const float*)d_in[4];  // (3072,)
    const float* bvec   = (const float*)d_in[5];  // (4096,)
    const float* lin_w  = (const float*)d_in[6];  // (256,512)
    const float* lin_b  = (const float*)d_in[7];  // (256,)
    float* out = (float*)d_out;
    char* ws = (char*)d_ws;

    short* RRbp  = (short*)(ws + WS_RRBP);
    short* Wp_hi = (short*)(ws + WS_WP_HI);
    short* Wp_lo = (short*)(ws + WS_WP_LO);
    short* Rt_hi = (short*)(ws + WS_RT_HI);
    short* Rt_lo = (short*)(ws + WS_RT_LO);
    short* Wt_hi = (short*)(ws + WS_WT_HI);
    short* Wt_lo = (short*)(ws + WS_WT_LO);
    short* in_hi = (short*)(ws + WS_IN_HI);
    short* in_lo = (short*)(ws + WS_IN_LO);
    short* Wpt   = (short*)(ws + WS_WPT);
    short* lwb   = (short*)(ws + WS_LWB);
    int*   doneG = (int*)(ws + WS_DONEG);
    int*   pready= (int*)(ws + WS_PREADY);
    int*   cdone = (int*)(ws + WS_CDONE);
    short* hpk0  = (short*)(ws + WS_HPK0);
    short* hpk1  = (short*)(ws + WS_HPK1);
    short* h_bf  = (short*)(ws + WS_HBF);
    float* xg0   = (float*)(ws + WS_XG0);
    float* xg1   = (float*)(ws + WS_XG1);
    short* hp_bf = (short*)(ws + WS_HPBF);
    float* RRbuf = (float*)(ws + WS_RRBUF);   // dead before persistent kernel

    hipMemsetAsync(hpk0, 0, 131072, stream);              // t=0 state
    hipMemsetAsync(doneG, 0, 32768 + 8192 + 8192, stream); // doneG+pready+cdone

    // ---- prepack weights/inputs into bf16 (hi/lo) planes ----
    split_copy<<<(H_DIM * P_DIM + 255) / 256, 256, 0, stream>>>(W_proj, Wp_hi, Wp_lo, H_DIM * P_DIM);
    split_copy<<<(B_SZ * T_SZ * I_DIM + 255) / 256, 256, 0, stream>>>(inp, in_hi, in_lo, B_SZ * T_SZ * I_DIM);
    split_copy<<<(O_DIM * P_DIM + 255) / 256, 256, 0, stream>>>(lin_w, lwb, nullptr, O_DIM * P_DIM);
    transpose_split<<<dim3(G4 / 32, P_DIM / 32), dim3(32, 8), 0, stream>>>(R, Rt_hi, Rt_lo, P_DIM, G4);
    transpose_split<<<dim3(G4 / 32, I_DIM / 32), dim3(32, 8), 0, stream>>>(W, Wt_hi, Wt_lo, I_DIM, G4);
    transpose_split<<<dim3(P_DIM / 32, H_DIM / 32), dim3(32, 8), 0, stream>>>(W_proj, Wpt, nullptr, H_DIM, P_DIM);

    // ---- RR = W_proj @ R (split, ~f32 precision), pack to B-fragments ----
    gemm_rr<<<dim3(G4 / 128, H_DIM / 128), 256, 0, stream>>>(
        Wp_hi, Wp_lo, Rt_hi, Rt_lo, nullptr, RRbuf, G4, P_DIM, 0);
    pack_rr<<<2048, 256, 0, stream>>>(RRbuf, RRbp);

    // ---- persistent producer/consumer recurrence (one kernel) ----
    lstm_persistent<<<256, 256, 0, stream>>>(
        in_hi, in_lo, Wt_hi, Wt_lo, bvec, RRbp, xg0, xg1,
        hpk0, hpk1, h_bf, p, doneG, pready, cdone);

    // ---- hp = h @ W_proj (single-pass bf16, bf16 output) ----
    gemm_proj<<<dim3(P_DIM / 128, 16384 / 128), 256, 0, stream>>>(
        h_bf, nullptr, Wpt, nullptr, nullptr, hp_bf, P_DIM, H_DIM, 0);

    // ---- out = hp @ lin_w^T + lin_b (single-pass bf16, f32 remapped out) ----
    gemm_out<<<dim3(O_DIM / 128, 16384 / 128), 256, 0, stream>>>(
        hp_bf, nullptr, lwb, nullptr, lin_b, out, O_DIM, P_DIM, 0);
}

// Round 9
// 2555.047 us; speedup vs baseline: 2.9863x; 2.9863x over previous
//
#include <hip/hip_runtime.h>
#include <math.h>

// Problem dims
#define B_SZ   32
#define T_SZ   512
#define I_DIM  256
#define H_DIM  1024
#define P_DIM  512
#define G4     4096   // 4*H
#define O_DIM  256

typedef short short8 __attribute__((ext_vector_type(8)));
typedef float f32x4  __attribute__((ext_vector_type(4)));

__device__ __forceinline__ float sigmf(float x) { return 1.0f / (1.0f + __expf(-x)); }
__device__ __forceinline__ float tanhfast(float x) { return 1.0f - 2.0f / (__expf(2.0f * x) + 1.0f); }
__device__ __forceinline__ short f2bf(float f) {
    union { float f; unsigned u; } v; v.f = f;
    unsigned r = (v.u + 0x7FFF + ((v.u >> 16) & 1)) >> 16;
    return (short)r;
}
__device__ __forceinline__ float bf2f(short h) {
    union { unsigned u; float f; } v; v.u = ((unsigned)(unsigned short)h) << 16;
    return v.f;
}

// ---------------------------------------------------------------------------
__global__ void split_copy(const float* __restrict__ in, short* __restrict__ hi,
                           short* __restrict__ lo, int n)
{
    int i = blockIdx.x * 256 + threadIdx.x;
    if (i < n) {
        float v = in[i];
        short h = f2bf(v);
        hi[i] = h;
        if (lo) lo[i] = f2bf(v - bf2f(h));
    }
}

__global__ void transpose_split(const float* __restrict__ in, short* __restrict__ hi,
                                short* __restrict__ lo, int rows, int cols)
{
    __shared__ float t[32][33];
    int c0 = blockIdx.x * 32, r0 = blockIdx.y * 32;
    int x = threadIdx.x, y = threadIdx.y;   // 32 x 8
    #pragma unroll
    for (int i = y; i < 32; i += 8) t[i][x] = in[(size_t)(r0 + i) * cols + c0 + x];
    __syncthreads();
    #pragma unroll
    for (int i = y; i < 32; i += 8) {
        float v = t[x][i];
        short h = f2bf(v);
        size_t o = (size_t)(c0 + i) * rows + r0 + x;
        hi[o] = h;
        if (lo) lo[o] = f2bf(v - bf2f(h));
    }
}

// ---------------------------------------------------------------------------
// MFMA bf16 GEMM tile body (one 128x128 C tile at m0,n0). Same as rounds 4-8.
// ---------------------------------------------------------------------------
template<int SPLIT, int AMODE, int CMODE, int BIAS>
__device__ __forceinline__
void gemm_tile(const short* __restrict__ Ah, const short* __restrict__ Al,
               const short* __restrict__ Bh, const short* __restrict__ Bl,
               const float* __restrict__ bias, void* __restrict__ Cp,
               int N, int K, int t0, int m0, int n0)
{
    __shared__ short As[SPLIT + 1][8192];   // [plane][row*64 + k], 16KB each
    __shared__ short Bs[SPLIT + 1][8192];
    const int tid = threadIdx.x;
    const int l   = tid & 63;
    const int w   = tid >> 6;
    const int wm  = w & 1, wn = w >> 1;

    f32x4 acc[4][4] = {};

    for (int k0 = 0; k0 < K; k0 += 64) {
        __syncthreads();
        #pragma unroll
        for (int q = 0; q < 4; q++) {
            int rg   = q * 4 + w;
            int rr   = (rg << 3) + (l >> 3);
            int slot = (l & 7) ^ (rr & 7);        // pre-swizzled source slot
            int lidx = rg * 512 + l * 8;          // linear LDS dest (shorts)
            size_t aoff, boff;
            int ra = m0 + rr, rb = n0 + rr;
            if constexpr (AMODE == 1)
                aoff = (size_t)((ra & 31) * 512 + t0 + (ra >> 5)) * 256 + k0 + slot * 8;
            else
                aoff = (size_t)ra * K + k0 + slot * 8;
            boff = (size_t)rb * K + k0 + slot * 8;
            __builtin_amdgcn_global_load_lds(Ah + aoff, &As[0][lidx], 16, 0, 0);
            __builtin_amdgcn_global_load_lds(Bh + boff, &Bs[0][lidx], 16, 0, 0);
            if constexpr (SPLIT) {
                __builtin_amdgcn_global_load_lds(Al + aoff, &As[1][lidx], 16, 0, 0);
                __builtin_amdgcn_global_load_lds(Bl + boff, &Bs[1][lidx], 16, 0, 0);
            }
        }
        __syncthreads();

        #pragma unroll
        for (int ks = 0; ks < 2; ks++) {
            const int cb = (((ks * 4) + (l >> 4)) ^ (l & 7)) * 16;  // swizzled col byte
            short8 af[4], bfr[4], afl[4], bfl[4];
            #pragma unroll
            for (int mf = 0; mf < 4; mf++) {
                int mloc = wm * 64 + mf * 16 + (l & 15);
                af[mf] = *(const short8*)((const char*)As[0] + mloc * 128 + cb);
                if constexpr (SPLIT)
                    afl[mf] = *(const short8*)((const char*)As[1] + mloc * 128 + cb);
            }
            #pragma unroll
            for (int nf = 0; nf < 4; nf++) {
                int nloc = wn * 64 + nf * 16 + (l & 15);
                bfr[nf] = *(const short8*)((const char*)Bs[0] + nloc * 128 + cb);
                if constexpr (SPLIT)
                    bfl[nf] = *(const short8*)((const char*)Bs[1] + nloc * 128 + cb);
            }
            #pragma unroll
            for (int mf = 0; mf < 4; mf++)
                #pragma unroll
                for (int nf = 0; nf < 4; nf++)
                    acc[mf][nf] = __builtin_amdgcn_mfma_f32_16x16x32_bf16(
                        af[mf], bfr[nf], acc[mf][nf], 0, 0, 0);
            if constexpr (SPLIT) {
                #pragma unroll
                for (int mf = 0; mf < 4; mf++)
                    #pragma unroll
                    for (int nf = 0; nf < 4; nf++)
                        acc[mf][nf] = __builtin_amdgcn_mfma_f32_16x16x32_bf16(
                            af[mf], bfl[nf], acc[mf][nf], 0, 0, 0);
                #pragma unroll
                for (int mf = 0; mf < 4; mf++)
                    #pragma unroll
                    for (int nf = 0; nf < 4; nf++)
                        acc[mf][nf] = __builtin_amdgcn_mfma_f32_16x16x32_bf16(
                            afl[mf], bfr[nf], acc[mf][nf], 0, 0, 0);
            }
        }
    }

    float bv[4];
    if constexpr (BIAS) {
        #pragma unroll
        for (int nf = 0; nf < 4; nf++)
            bv[nf] = bias[n0 + wn * 64 + nf * 16 + (l & 15)];
    }
    #pragma unroll
    for (int mf = 0; mf < 4; mf++) {
        #pragma unroll
        for (int r = 0; r < 4; r++) {
            int row = m0 + wm * 64 + mf * 16 + (l >> 4) * 4 + r;
            #pragma unroll
            for (int nf = 0; nf < 4; nf++) {
                int col = n0 + wn * 64 + nf * 16 + (l & 15);
                float v = acc[mf][nf][r];
                if constexpr (BIAS) v += bv[nf];
                if constexpr (CMODE == 0)
                    ((float*)Cp)[(size_t)row * N + col] = v;
                else if constexpr (CMODE == 1)
                    ((short*)Cp)[(size_t)row * N + col] = f2bf(v);
                else
                    ((float*)Cp)[(size_t)(row & 31) * (T_SZ * O_DIM)
                                 + (size_t)(row >> 5) * O_DIM + col] = v;
            }
        }
    }
}

// ---- concrete (non-template) kernel entry points ----
__global__ __launch_bounds__(256)
void gemm_rr(const short* Ah, const short* Al, const short* Bh, const short* Bl,
             const float* bias, void* Cp, int N, int K, int t0)
{ gemm_tile<1, 0, 0, 0>(Ah, Al, Bh, Bl, bias, Cp, N, K, t0, blockIdx.y * 128, blockIdx.x * 128); }

__global__ __launch_bounds__(256)
void gemm_xg(const short* Ah, const short* Al, const short* Bh, const short* Bl,
             const float* bias, void* Cp, int N, int K, int t0)
{ gemm_tile<1, 1, 0, 1>(Ah, Al, Bh, Bl, bias, Cp, N, K, t0, blockIdx.y * 128, blockIdx.x * 128); }

__global__ __launch_bounds__(256)
void gemm_proj(const short* Ah, const short* Al, const short* Bh, const short* Bl,
               const float* bias, void* Cp, int N, int K, int t0)
{ gemm_tile<0, 0, 1, 0>(Ah, Al, Bh, Bl, bias, Cp, N, K, t0, blockIdx.y * 128, blockIdx.x * 128); }

__global__ __launch_bounds__(256)
void gemm_out(const short* Ah, const short* Al, const short* Bh, const short* Bl,
              const float* bias, void* Cp, int N, int K, int t0)
{ gemm_tile<0, 0, 2, 1>(Ah, Al, Bh, Bl, bias, Cp, N, K, t0, blockIdx.y * 128, blockIdx.x * 128); }

// ---------------------------------------------------------------------------
// Pack RR (f32 [1024 k][4096 gatecol]) into per-block MFMA B-fragment order
// for 256 step-blocks of 16 gatecols (4 j x 4 gates):
// RRbp[blk 256][kt 32][lane 64][i 8]; nl=lane&15 -> g=nl>>2, jl=nl&3,
// col = g*1024 + blk*4 + jl; k = kt*32 + (lane>>4)*8 + i  (same k-slot
// formula as the hout A-pack, so k-permutation ambiguity cancels).
// ---------------------------------------------------------------------------
__global__ __launch_bounds__(256)
void pack_rr(const float* __restrict__ RRf, short* __restrict__ RRbp)
{
    int idx = blockIdx.x * 256 + threadIdx.x;     // short8 slot, 0..524287
    int lane = idx & 63;
    int kt   = (idx >> 6) & 31;
    int blk  = idx >> 11;
    int nl = lane & 15;
    int g = nl >> 2, jl = nl & 3;
    int col = g * 1024 + blk * 4 + jl;
    int kbase = kt * 32 + (lane >> 4) * 8;
    short8 v;
    #pragma unroll
    for (int i = 0; i < 8; i++)
        v[i] = f2bf(RRf[(size_t)(kbase + i) * G4 + col]);
    ((short8*)RRbp)[idx] = v;
}

// ---------------------------------------------------------------------------
// One LSTM step via MFMA. Grid: 256 blocks (4 j-cols each), 256 threads.
// 4 waves = (wm batch-half) x (kh K-half); per wave 16 MFMA + 32x16B loads.
// K-half partials reduced via zbuf LDS; epilogue 128 threads (32b x 4j).
// A from hpk_in [2 mh][32 kt][64 lane][8] bf16; B from RRbp (see pack_rr).
// c lives in global c_st; h written to h_bf (row-major) + hpk_out (A-pack).
// ---------------------------------------------------------------------------
__global__ __launch_bounds__(256)
void lstm_step(const float* __restrict__ xg_t,
               const short* __restrict__ RRbp,
               const short* __restrict__ hp_in,
               short* __restrict__ hp_out,
               short* __restrict__ h_bf_t,
               float* __restrict__ c_st,
               const float* __restrict__ p)
{
    __shared__ float zbuf[2][32][17];
    const int tid  = threadIdx.x;
    const int bid  = blockIdx.x;          // j0 = bid*4
    const int lane = tid & 63;
    const int w    = tid >> 6;
    const int wm   = w & 1;               // batch half
    const int kh   = w >> 1;              // K half

    const short8* Ap = (const short8*)hp_in + (size_t)(wm * 32 + kh * 16) * 64 + lane;
    const short8* Bp = (const short8*)RRbp + (size_t)(bid * 32 + kh * 16) * 64 + lane;

    f32x4 acc0 = {0.f, 0.f, 0.f, 0.f};
    f32x4 acc1 = {0.f, 0.f, 0.f, 0.f};
    #pragma unroll
    for (int i = 0; i < 8; i++) {
        short8 a = Ap[(size_t)i * 64];
        short8 b = Bp[(size_t)i * 64];
        acc0 = __builtin_amdgcn_mfma_f32_16x16x32_bf16(a, b, acc0, 0, 0, 0);
    }
    #pragma unroll
    for (int i = 8; i < 16; i++) {
        short8 a = Ap[(size_t)i * 64];
        short8 b = Bp[(size_t)i * 64];
        acc1 = __builtin_amdgcn_mfma_f32_16x16x32_bf16(a, b, acc1, 0, 0, 0);
    }
    acc0[0] += acc1[0]; acc0[1] += acc1[1]; acc0[2] += acc1[2]; acc0[3] += acc1[3];

    {   // C/D layout: col=lane&15, row=(lane>>4)*4+r  (row = batch-in-half)
        int col = lane & 15;
        int row = (lane >> 4) * 4;
        #pragma unroll
        for (int r = 0; r < 4; r++)
            zbuf[kh][wm * 16 + row + r][col] = acc0[r];
    }
    __syncthreads();

    if (tid < 128) {     // epilogue: thread (b = tid>>2, jl = tid&3)
        int b = tid >> 2, jl = tid & 3;
        int j = bid * 4 + jl;
        float zi = zbuf[0][b][jl]      + zbuf[1][b][jl]      + xg_t[(size_t)b * G4 + j];
        float zf = zbuf[0][b][4 + jl]  + zbuf[1][b][4 + jl]  + xg_t[(size_t)b * G4 + 1024 + j];
        float zg = zbuf[0][b][8 + jl]  + zbuf[1][b][8 + jl]  + xg_t[(size_t)b * G4 + 2048 + j];
        float zo = zbuf[0][b][12 + jl] + zbuf[1][b][12 + jl] + xg_t[(size_t)b * G4 + 3072 + j];
        float cv = c_st[b * H_DIM + j];
        float ig = sigmf(zi + cv * p[j]);
        float fg = sigmf(zf + cv * p[1024 + j]);
        float gg = tanhfast(zg);
        float cn = fg * cv + ig * gg;
        float og = sigmf(zo + cn * p[2048 + j]);
        float hv = og * tanhfast(cn);
        short hb = f2bf(hv);
        c_st[b * H_DIM + j]   = cn;
        h_bf_t[b * H_DIM + j] = hb;
        // write h in A-fragment order for next step (same k-slot formula)
        int lane2 = (b & 15) | (((j & 31) >> 3) << 4);
        int kt2   = j >> 5;
        int wm2   = b >> 4;
        hp_out[(size_t)(((wm2 * 32 + kt2) * 64 + lane2)) * 8 + (j & 7)] = hb;
    }
}

// ---------------------------------------------------------------------------
extern "C" void kernel_launch(void* const* d_in, const int* in_sizes, int n_in,
                              void* d_out, int out_size, void* d_ws, size_t ws_size,
                              hipStream_t stream)
{
    const float* inp    = (const float*)d_in[0];  // (32,512,256)
    const float* W      = (const float*)d_in[1];  // (256,4096)
    const float* R      = (const float*)d_in[2];  // (512,4096)
    const float* W_proj = (const float*)d_in[3];  // (1024,512)
    const float* p      = (const float*)d_in[4];  // (3072,)
    const float* bvec   = (const float*)d_in[5];  // (4096,)
    const float* lin_w  = (const float*)d_in[6];  // (256,512)
    const float* lin_b  = (const float*)d_in[7];  // (256,)
    float* out = (float*)d_out;
    char* ws = (char*)d_ws;

    float* RRbuf = (float*)(ws + 0);              // 16 MB
    short* RRbp  = (short*)(ws + 16777216);       // 8 MB
    short* Wp_hi = (short*)(ws + 25165824);       // 1 MB
    short* Wp_lo = (short*)(ws + 26214400);
    short* Rt_hi = (short*)(ws + 27262976);       // 4 MB  (R^T planes [4096][512])
    short* Rt_lo = (short*)(ws + 31457280);
    short* Wt_hi = (short*)(ws + 35651584);       // 2 MB  (W^T planes [4096][256])
    short* Wt_lo = (short*)(ws + 37748736);
    short* in_hi = (short*)(ws + 39845888);       // 8 MB  (inputs planes, row-major)
    short* in_lo = (short*)(ws + 48234496);
    short* Wpt   = (short*)(ws + 56623104);       // 1 MB  (W_proj^T bf16 [512][1024])
    short* lwb   = (short*)(ws + 57671680);       // 256 KB (lin_w bf16 [256][512])
    float* c_st  = (float*)(ws + 57933824);       // 128 KB
    short* hpk0  = (short*)(ws + 58064896);       // 64 KB
    short* hpk1  = (short*)(ws + 58130432);       // 64 KB
    short* h_bf  = (short*)(ws + 58195968);       // 32 MB  ([512][32][1024] bf16)
    float* xg_c  = (float*)(ws + 91750400);       // 32 MB  (64-step chunk, f32)
    short* hp_bf = (short*)(ws + 125304832);      // 16 MB  ([16384][512] bf16)
    // requires ws_size >= 142,082,048 bytes

    hipMemsetAsync(hpk0, 0, 65536, stream);
    hipMemsetAsync(c_st, 0, B_SZ * H_DIM * sizeof(float), stream);

    // ---- prepack weights/inputs into bf16 (hi/lo) planes ----
    split_copy<<<(H_DIM * P_DIM + 255) / 256, 256, 0, stream>>>(W_proj, Wp_hi, Wp_lo, H_DIM * P_DIM);
    split_copy<<<(B_SZ * T_SZ * I_DIM + 255) / 256, 256, 0, stream>>>(inp, in_hi, in_lo, B_SZ * T_SZ * I_DIM);
    split_copy<<<(O_DIM * P_DIM + 255) / 256, 256, 0, stream>>>(lin_w, lwb, nullptr, O_DIM * P_DIM);
    transpose_split<<<dim3(G4 / 32, P_DIM / 32), dim3(32, 8), 0, stream>>>(R, Rt_hi, Rt_lo, P_DIM, G4);
    transpose_split<<<dim3(G4 / 32, I_DIM / 32), dim3(32, 8), 0, stream>>>(W, Wt_hi, Wt_lo, I_DIM, G4);
    transpose_split<<<dim3(P_DIM / 32, H_DIM / 32), dim3(32, 8), 0, stream>>>(W_proj, Wpt, nullptr, H_DIM, P_DIM);

    // ---- RR = W_proj @ R (split, ~f32 precision), pack to B-fragments ----
    gemm_rr<<<dim3(G4 / 128, H_DIM / 128), 256, 0, stream>>>(
        Wp_hi, Wp_lo, Rt_hi, Rt_lo, nullptr, RRbuf, G4, P_DIM, 0);
    pack_rr<<<2048, 256, 0, stream>>>(RRbuf, RRbp);

    // ---- recurrence in 8 chunks of 64 steps (multi-launch, graph-replayed) ----
    for (int chunk = 0; chunk < 8; chunk++) {
        int t0 = chunk * 64;
        gemm_xg<<<dim3(G4 / 128, 2048 / 128), 256, 0, stream>>>(
            in_hi, in_lo, Wt_hi, Wt_lo, bvec, xg_c, G4, I_DIM, t0);
        for (int tl = 0; tl < 64; tl++) {
            int t = t0 + tl;
            short* hin  = (t & 1) ? hpk1 : hpk0;
            short* hout = (t & 1) ? hpk0 : hpk1;
            lstm_step<<<256, 256, 0, stream>>>(
                xg_c + (size_t)tl * B_SZ * G4, RRbp, hin, hout,
                h_bf + (size_t)t * (B_SZ * H_DIM), c_st, p);
        }
    }

    // ---- hp = h @ W_proj (single-pass bf16, bf16 output) ----
    gemm_proj<<<dim3(P_DIM / 128, 16384 / 128), 256, 0, stream>>>(
        h_bf, nullptr, Wpt, nullptr, nullptr, hp_bf, P_DIM, H_DIM, 0);

    // ---- out = hp @ lin_w^T + lin_b (single-pass bf16, f32 remapped out) ----
    gemm_out<<<dim3(O_DIM / 128, 16384 / 128), 256, 0, stream>>>(
        hp_bf, nullptr, lwb, nullptr, lin_b, out, O_DIM, P_DIM, 0);
}